// Round 8
// baseline (724.004 us; speedup 1.0000x reference)
//
#include <hip/hip_runtime.h>

#define N_NODES 100000
#define NPAD    100096      // multiple of 128 so layer blocks need no row clamp
#define N_EDGES 1600000
#define FDIM 128
#define GDIM 64
#define CDIM 10

#define LROWS 128           // nodes per layer block == bucket size
#define NBK   782           // NPAD / LROWS buckets
#define CAP   2560          // bucket capacity: lambda=2046, sigma~45 -> +11sigma

typedef unsigned short us16;
typedef unsigned char u8;
typedef us16 usx8 __attribute__((ext_vector_type(8)));
typedef short bfrag __attribute__((ext_vector_type(8)));   // 8 bf16 = 4 VGPRs
typedef float f32x4 __attribute__((ext_vector_type(4)));
typedef float f32x2 __attribute__((ext_vector_type(2)));

__device__ __forceinline__ float bf2f(us16 u) {
  return __uint_as_float(((unsigned)u) << 16);
}
__device__ __forceinline__ us16 f2bf(float f) {
  unsigned u = __float_as_uint(f);
  u += 0x7FFFu + ((u >> 16) & 1u);   // RNE
  return (us16)(u >> 16);
}

// accumulate 8 fp8 (e4m3, one uint2) into a[0..8)
__device__ __forceinline__ void acc_fp8x8(uint2 v, float* a) {
  f32x2 p0 = __builtin_amdgcn_cvt_pk_f32_fp8(v.x, false);
  f32x2 p1 = __builtin_amdgcn_cvt_pk_f32_fp8(v.x, true);
  f32x2 p2 = __builtin_amdgcn_cvt_pk_f32_fp8(v.y, false);
  f32x2 p3 = __builtin_amdgcn_cvt_pk_f32_fp8(v.y, true);
  a[0] += p0[0]; a[1] += p0[1]; a[2] += p1[0]; a[3] += p1[1];
  a[4] += p2[0]; a[5] += p2[1]; a[6] += p3[0]; a[7] += p3[1];
}

// ---------------- prep: cast x (bf16 + fp8), pack W, zero pooled --------------
// No edge histogram any more: fixed-capacity buckets removed the need for
// counts/scans entirely. R4 lesson stands: no per-node global degree atomics.
#define XB 6250            // N_NODES*FDIM/8/256 cast blocks
__global__ __launch_bounds__(256) void k_prep(
    const float* __restrict__ x, us16* __restrict__ xb, u8* __restrict__ xq,
    const float* __restrict__ Wrel1, const float* __restrict__ Wroot1,
    const float* __restrict__ Wrel2, const float* __restrict__ Wroot2,
    const float* __restrict__ Wrel3, const float* __restrict__ Wroot3,
    us16* __restrict__ Wp, float* __restrict__ pooled) {
  int bx = blockIdx.x, tid = threadIdx.x;
  if (bx < XB) {
    size_t i = ((size_t)bx * 256 + tid) * 8;    // 8 floats per thread
    float4 a = *(const float4*)(x + i);
    float4 b = *(const float4*)(x + i + 4);
    usx8 o;
    o[0]=f2bf(a.x); o[1]=f2bf(a.y); o[2]=f2bf(a.z); o[3]=f2bf(a.w);
    o[4]=f2bf(b.x); o[5]=f2bf(b.y); o[6]=f2bf(b.z); o[7]=f2bf(b.w);
    *(usx8*)(xb + i) = o;
    int lo = __builtin_amdgcn_cvt_pk_fp8_f32(a.x, a.y, 0, false);
    lo     = __builtin_amdgcn_cvt_pk_fp8_f32(a.z, a.w, lo, true);
    int hi = __builtin_amdgcn_cvt_pk_fp8_f32(b.x, b.y, 0, false);
    hi     = __builtin_amdgcn_cvt_pk_fp8_f32(b.z, b.w, hi, true);
    uint2 q; q.x = (unsigned)lo; q.y = (unsigned)hi;
    *(uint2*)(xq + i) = q;                       // 8 B contiguous per thread
  } else if (bx < XB + 384) {
    int wb = bx - XB;             // 0..383
    int l = wb >> 7;              // layer
    const float* Wrel  = (l == 0) ? Wrel1  : (l == 1) ? Wrel2  : Wrel3;
    const float* Wroot = (l == 0) ? Wroot1 : (l == 1) ? Wroot2 : Wroot3;
    int idx = (wb & 127) * 256 + tid;   // 0..32767
    int k = idx >> 7;       // 0..255
    int c = idx & 127;      // output col
    float v = (k < 128) ? Wrel[c * 128 + k] : Wroot[c * 128 + k - 128];
    Wp[(size_t)l * 32768 + (((k >> 3) * 128 + c) << 3) + (k & 7)] = f2bf(v);
  } else {
    for (int i = tid; i < GDIM * FDIM; i += 256) pooled[i] = 0.f;
  }
}

// ---------------- escatter: one returning atomic per edge ---------------------
// 1.6M atomicAdds over 782 counters (3 KB, L2-hot; ~2K increments each).
// ebuf lines (8 MB region) are touched repeatedly while filling -> they stay
// dirty in L2 and write back as FULL lines (unlike R4's 105MB once-partially-
// touched disaster). Record packed (src << 7) | dst_local.
__global__ __launch_bounds__(1024) void k_escatter(
    const int* __restrict__ src, const int* __restrict__ dst,
    int* __restrict__ bcur, int* __restrict__ ebuf) {
  int i = blockIdx.x * 1024 + threadIdx.x;
  if (i < N_EDGES) {
    int d = dst[i];
    int b = d >> 7;
    int lp = atomicAdd(&bcur[b], 1);
    if (lp < CAP) ebuf[b * CAP + lp] = (src[i] << 7) | (d & (LROWS - 1));
  }
}

// ---------------- fused layer: [sort] -> fp8 gather -> MFMA dual GEMM ---------
// out = relu(agg(hq_in) @ Wrel^T + hin @ Wroot^T + b).
// MODE=1 (layer 1): phase 0 sorts the block's own bucket run from ebuf in LDS
//   (hist-128 + shuffle scan + cursor scatter -> elist), gathers from the LDS
//   elist, and dumps csr/row_ptr/row_end for layers 2/3.
// MODE=0 (layers 2/3): reads row_ptr/row_end/csr from global as in R7.
// Gather path is R7's proven fp8 structure byte-for-byte.
#define ASTR 136
template<int MODE>
__global__ __launch_bounds__(512) void k_layer(
    const us16* __restrict__ hin, const u8* __restrict__ hq_in,
    const us16* __restrict__ Wp, const float* __restrict__ bias,
    int* __restrict__ row_ptr, int* __restrict__ row_end,
    int* __restrict__ csr, const int* __restrict__ ebuf,
    const int* __restrict__ bcur,
    us16* __restrict__ out, u8* __restrict__ hq_out,
    const int* __restrict__ batch, float* __restrict__ pooled) {
  __shared__ us16 As[LROWS * ASTR];              // 34.8 KB
  __shared__ int rp[MODE ? (LROWS + 1) : 1];     // per-node offsets (MODE1)
  __shared__ int cur[MODE ? LROWS : 1];
  __shared__ int elist[MODE ? CAP : 1];          // 10 KB (MODE1)
  __shared__ int wfix[2];
  int tid = threadIdx.x;
  int bb = blockIdx.x;
  int node0 = bb * LROWS;

  if (MODE) {
    // ---- phase 0: sort own bucket run in LDS ----
    int cnt = bcur[bb]; if (cnt > CAP) cnt = CAP;
    if (tid < LROWS) rp[tid] = 0;
    __syncthreads();
    for (int i = tid; i < cnt; i += 512)
      atomicAdd(&rp[ebuf[bb * CAP + i] & (LROWS - 1)], 1);
    __syncthreads();
    int lane = tid & 63;
    int deg = 0, xs = 0;
    if (tid < LROWS) { deg = rp[tid]; xs = deg; }
#pragma unroll
    for (int d = 1; d < 64; d <<= 1) {
      int t = __shfl_up(xs, d, 64);
      if (lane >= d) xs += t;
    }
    if (tid < LROWS && lane == 63) wfix[tid >> 6] = xs;
    __syncthreads();
    if (tid < LROWS) {
      int ex = xs - deg + ((tid >= 64) ? wfix[0] : 0);   // exclusive
      rp[tid] = ex;
      cur[tid] = ex;
    }
    if (tid == 0) rp[LROWS] = cnt;
    __syncthreads();
    for (int i = tid; i < cnt; i += 512) {
      int e = ebuf[bb * CAP + i];
      int lp = atomicAdd(&cur[e & (LROWS - 1)], 1);
      elist[lp] = e >> 7;
    }
    __syncthreads();
    // dump for layers 2/3 (coalesced; csr shares ebuf's padded layout)
    int gb = bb * CAP;
    for (int i = tid; i < cnt; i += 512) csr[gb + i] = elist[i];
    if (tid < LROWS) {
      int n = node0 + tid;
      if (n < N_NODES) {
        row_ptr[n] = gb + rp[tid];
        row_end[n] = gb + rp[tid + 1];
      }
    }
  }

  // ---- phase 1: aggregate 128 nodes (4 rounds x 32 concurrent), fp8 rows ----
  int slot = tid >> 4;      // 0..31: node slot within round
  int lane16 = tid & 15;    // feature octet
  const u8* gbase = hq_in + lane16 * 8;   // 8 fp8 features per lane
#pragma unroll 1
  for (int rnd = 0; rnd < 4; ++rnd) {
    int node = node0 + rnd * 32 + slot;
    float a[8];
#pragma unroll
    for (int j = 0; j < 8; ++j) a[j] = 0.f;
    int s, e;
    if (MODE) {
      s = rp[rnd * 32 + slot]; e = rp[rnd * 32 + slot + 1];
    } else {
      s = 0; e = 0;
      if (node < N_NODES) { s = row_ptr[node]; e = row_end[node]; }
    }
    int p = s;
    for (; p + 4 <= e; p += 4) {
      int j0, j1, j2, j3;
      if (MODE) {
        j0 = elist[p];     j1 = elist[p + 1];
        j2 = elist[p + 2]; j3 = elist[p + 3];
      } else {
        j0 = csr[p];       j1 = csr[p + 1];
        j2 = csr[p + 2];   j3 = csr[p + 3];
      }
      uint2 v0 = *(const uint2*)(gbase + (size_t)j0 * FDIM);
      uint2 v1 = *(const uint2*)(gbase + (size_t)j1 * FDIM);
      uint2 v2 = *(const uint2*)(gbase + (size_t)j2 * FDIM);
      uint2 v3 = *(const uint2*)(gbase + (size_t)j3 * FDIM);
      acc_fp8x8(v0, a); acc_fp8x8(v1, a);
      acc_fp8x8(v2, a); acc_fp8x8(v3, a);
    }
    for (; p < e; ++p) {
      int j = MODE ? elist[p] : csr[p];
      uint2 v = *(const uint2*)(gbase + (size_t)j * FDIM);
      acc_fp8x8(v, a);
    }
    usx8 o;
#pragma unroll
    for (int j = 0; j < 8; ++j) o[j] = f2bf(a[j]);
    *(usx8*)&As[(rnd * 32 + slot) * ASTR + lane16 * 8] = o;
  }
  __syncthreads();

  // ---- phase 2: MFMA.  A agg-half from LDS, root-half from global (bf16),
  //      W b-frags straight from L1/L2.
  int wave = tid >> 6, lane = tid & 63;
  int m = lane & 15, quad = lane >> 4;
  size_t rowA = (size_t)(node0 + wave * 16 + m);
  const us16* baseH = hin + rowA * FDIM + quad * 8;
  const us16* aldsb = &As[(wave * 16 + m) * ASTR + quad * 8];
  f32x4 acc[8];
#pragma unroll
  for (int t = 0; t < 8; ++t) acc[t] = (f32x4){0.f, 0.f, 0.f, 0.f};

#pragma unroll 1
  for (int c = 0; c < 8; ++c) {
    bfrag a;
    if (c < 4) a = *(const bfrag*)(aldsb + c * 32);
    else       a = *(const bfrag*)(baseH + (c - 4) * 32);
    int kq = c * 4 + quad;
    const us16* wbase = Wp + (((size_t)kq * 128 + m) << 3);
#pragma unroll
    for (int t = 0; t < 8; ++t) {
      bfrag b = *(const bfrag*)(wbase + t * 128);   // 16 cols * 8 j
      acc[t] = __builtin_amdgcn_mfma_f32_16x16x32_bf16(a, b, acc[t], 0, 0, 0);
    }
  }
  // epilogue: D lane mapping col = lane&15 (within t-tile), row = quad*4 + i
  int w16 = node0 + wave * 16;
  int orow0 = w16 + quad * 4;
  if (pooled == nullptr) {
#pragma unroll
    for (int t = 0; t < 8; ++t) {
      int col = t * 16 + m;
      float bv = bias[col];
#pragma unroll
      for (int i = 0; i < 4; ++i) {
        int r = orow0 + i;
        if (r < N_NODES) {
          float val = fmaxf(acc[t][i] + bv, 0.f);
          out[(size_t)r * FDIM + col] = f2bf(val);
          // fp8 copy for next layer's gather; wave covers full 128B rows.
          hq_out[(size_t)r * FDIM + col] =
              (u8)(__builtin_amdgcn_cvt_pk_fp8_f32(val, val, 0, false) & 0xFF);
        }
      }
    }
  } else {
    // fused mean-pool (sum phase): no global store of h3
    int rlast = w16 + 15;
    int gfirst = batch[(w16 < N_NODES) ? w16 : (N_NODES - 1)];
    int glast  = batch[(rlast < N_NODES) ? rlast : (N_NODES - 1)];
    bool uniform = (gfirst == glast) && (rlast < N_NODES);
    if (uniform) {
#pragma unroll
      for (int t = 0; t < 8; ++t) {
        int col = t * 16 + m;
        float bv = bias[col];
        float v = fmaxf(acc[t][0] + bv, 0.f) + fmaxf(acc[t][1] + bv, 0.f) +
                  fmaxf(acc[t][2] + bv, 0.f) + fmaxf(acc[t][3] + bv, 0.f);
        v += __shfl_xor(v, 16);
        v += __shfl_xor(v, 32);
        if (quad == 0) atomicAdd(&pooled[gfirst * FDIM + col], v);
      }
    } else {
      int g[4];
#pragma unroll
      for (int i = 0; i < 4; ++i) {
        int r = orow0 + i;
        g[i] = batch[(r < N_NODES) ? r : (N_NODES - 1)];
      }
#pragma unroll
      for (int t = 0; t < 8; ++t) {
        int col = t * 16 + m;
        float bv = bias[col];
#pragma unroll
        for (int i = 0; i < 4; ++i) {
          int r = orow0 + i;
          if (r < N_NODES)
            atomicAdd(&pooled[g[i] * FDIM + col], fmaxf(acc[t][i] + bv, 0.f));
        }
      }
    }
  }
}

// ---------------- MLP head + log_softmax (divides pooled sums by counts) ------
__global__ __launch_bounds__(128) void k_head(
    const float* __restrict__ pooled, const int* __restrict__ batch,
    const float* __restrict__ Wl1, const float* __restrict__ bl1,
    const float* __restrict__ Wl2, const float* __restrict__ bl2,
    float* __restrict__ out) {
  int g = blockIdx.x;
  __shared__ int sb[2];
  __shared__ float p[128];
  __shared__ float h1[64];
  __shared__ float logit[CDIM];
  if (threadIdx.x < 2) {
    int key = g + (int)threadIdx.x;
    int lo = 0, hi = N_NODES;
    while (lo < hi) {
      int mid = (lo + hi) >> 1;
      if (batch[mid] < key) lo = mid + 1; else hi = mid;
    }
    sb[threadIdx.x] = lo;
  }
  __syncthreads();
  float cnt = (float)(sb[1] - sb[0]);
  p[threadIdx.x] = pooled[g * FDIM + threadIdx.x] / fmaxf(cnt, 1.f);
  __syncthreads();
  if (threadIdx.x < 64) {
    float acc = bl1[threadIdx.x];
    for (int k = 0; k < 128; ++k) acc += p[k] * Wl1[threadIdx.x * 128 + k];
    h1[threadIdx.x] = fmaxf(acc, 0.f);
  }
  __syncthreads();
  if (threadIdx.x < CDIM) {
    float acc = bl2[threadIdx.x];
    for (int k = 0; k < 64; ++k) acc += h1[k] * Wl2[threadIdx.x * 64 + k];
    logit[threadIdx.x] = acc;
  }
  __syncthreads();
  if (threadIdx.x == 0) {
    float m = -1e30f;
    for (int c = 0; c < CDIM; ++c) m = fmaxf(m, logit[c]);
    float s = 0.f;
    for (int c = 0; c < CDIM; ++c) s += expf(logit[c] - m);
    float ls = logf(s);
    for (int c = 0; c < CDIM; ++c) out[g * CDIM + c] = logit[c] - m - ls;
  }
}

extern "C" void kernel_launch(void* const* d_in, const int* in_sizes, int n_in,
                              void* d_out, int out_size, void* d_ws, size_t ws_size,
                              hipStream_t stream) {
  const float* x      = (const float*)d_in[0];
  const int* edge_idx = (const int*)d_in[1];
  const int* batch    = (const int*)d_in[2];
  const float* W1_rel  = (const float*)d_in[4];
  const float* b1_rel  = (const float*)d_in[5];
  const float* W1_root = (const float*)d_in[6];
  const float* W2_rel  = (const float*)d_in[7];
  const float* b2_rel  = (const float*)d_in[8];
  const float* W2_root = (const float*)d_in[9];
  const float* W3_rel  = (const float*)d_in[10];
  const float* b3_rel  = (const float*)d_in[11];
  const float* W3_root = (const float*)d_in[12];
  const float* Wl1     = (const float*)d_in[13];
  const float* bl1     = (const float*)d_in[14];
  const float* Wl2     = (const float*)d_in[15];
  const float* bl2     = (const float*)d_in[16];
  const int* esrc = edge_idx;
  const int* edst = edge_idx + N_EDGES;

  char* ws = (char*)d_ws;
  size_t off = 0;
  auto alloc = [&](size_t bytes) {
    void* p = ws + off;
    off += (bytes + 255) & ~(size_t)255;
    return p;
  };
  int* row_ptr  = (int*)alloc((N_NODES + 1) * sizeof(int));
  int* row_end  = (int*)alloc(N_NODES * sizeof(int));
  int* bcur     = (int*)alloc(NBK * sizeof(int));
  int* csr      = (int*)alloc((size_t)NBK * CAP * sizeof(int));   // 8 MB padded
  int* ebuf     = (int*)alloc((size_t)NBK * CAP * sizeof(int));   // 8 MB padded
  us16* xb      = (us16*)alloc((size_t)NPAD * FDIM * sizeof(us16)); // h0, then h2
  us16* hA      = (us16*)alloc((size_t)NPAD * FDIM * sizeof(us16)); // h1
  u8*   xq      = (u8*)alloc((size_t)NPAD * FDIM);                  // q0, then q2
  u8*   hqA     = (u8*)alloc((size_t)NPAD * FDIM);                  // q1
  us16* Wp      = (us16*)alloc(3 * 32768 * sizeof(us16));
  float* pooled = (float*)alloc(GDIM * FDIM * sizeof(float));

  hipMemsetAsync(bcur, 0, NBK * sizeof(int), stream);

  // prep: cast x (bf16+fp8), pack W, zero pooled (no histogram any more)
  k_prep<<<XB + 385, 256, 0, stream>>>(
      x, xb, xq, W1_rel, W1_root, W2_rel, W2_root, W3_rel, W3_root, Wp, pooled);

  // single-pass bucket scatter (782 fixed-capacity buckets)
  k_escatter<<<(N_EDGES + 1023) / 1024, 1024, 0, stream>>>(
      esrc, edst, bcur, ebuf);

  // layer 1 (MODE1): sorts its bucket in LDS, gathers q0, root xb -> hA/hqA;
  // dumps csr/row_ptr/row_end for layers 2/3.
  k_layer<1><<<NBK, 512, 0, stream>>>(xb, xq, Wp, b1_rel,
                                      row_ptr, row_end, csr, ebuf, bcur,
                                      hA, hqA, batch, nullptr);
  // layer 2 (MODE0): gather q1, root hA -> xb/xq (dead inputs reused)
  k_layer<0><<<NBK, 512, 0, stream>>>(hA, hqA, Wp + 32768, b2_rel,
                                      row_ptr, row_end, csr, nullptr, nullptr,
                                      xb, xq, batch, nullptr);
  // layer 3 (MODE0): gather q2, root xb -> pooled sums (no h3 store)
  k_layer<0><<<NBK, 512, 0, stream>>>(xb, xq, Wp + 65536, b3_rel,
                                      row_ptr, row_end, csr, nullptr, nullptr,
                                      hA, nullptr, batch, pooled);

  k_head<<<GDIM, 128, 0, stream>>>(pooled, batch, Wl1, bl1, Wl2, bl2, (float*)d_out);
}

// Round 9
// 378.189 us; speedup vs baseline: 1.9144x; 1.9144x over previous
//
#include <hip/hip_runtime.h>

#define N_NODES 100000
#define NPAD    100096      // multiple of 128 so layer blocks need no row clamp
#define N_EDGES 1600000
#define FDIM 128
#define GDIM 64
#define CDIM 10

#define BSH   9
#define BSIZE 512           // nodes per bucket
#define NB    196           // ceil(N_NODES / BSIZE)
#define EPB   8192          // edges per chunk (prep hist AND bscatter) -> 196 chunks
#define NCH   196           // ceil(N_EDGES / EPB)

typedef unsigned short us16;
typedef unsigned char u8;
typedef us16 usx8 __attribute__((ext_vector_type(8)));
typedef short bfrag __attribute__((ext_vector_type(8)));   // 8 bf16 = 4 VGPRs
typedef float f32x4 __attribute__((ext_vector_type(4)));
typedef float f32x2 __attribute__((ext_vector_type(2)));

__device__ __forceinline__ float bf2f(us16 u) {
  return __uint_as_float(((unsigned)u) << 16);
}
__device__ __forceinline__ us16 f2bf(float f) {
  unsigned u = __float_as_uint(f);
  u += 0x7FFFu + ((u >> 16) & 1u);   // RNE
  return (us16)(u >> 16);
}

// accumulate 8 fp8 (e4m3, one uint2) into a[0..8)
__device__ __forceinline__ void acc_fp8x8(uint2 v, float* a) {
  f32x2 p0 = __builtin_amdgcn_cvt_pk_f32_fp8(v.x, false);
  f32x2 p1 = __builtin_amdgcn_cvt_pk_f32_fp8(v.x, true);
  f32x2 p2 = __builtin_amdgcn_cvt_pk_f32_fp8(v.y, false);
  f32x2 p3 = __builtin_amdgcn_cvt_pk_f32_fp8(v.y, true);
  a[0] += p0[0]; a[1] += p0[1]; a[2] += p1[0]; a[3] += p1[1];
  a[4] += p2[0]; a[5] += p2[1]; a[6] += p3[0]; a[7] += p3[1];
}

// ---------------- prep: cast x (bf16 + fp8), pack W, zero pooled, histogram ---
// bcnt zeroed by memsetAsync BEFORE this kernel.
// Histogram chunks ALSO store their per-chunk hist row (chist, non-atomic,
// coalesced) so bscatter gets deterministic offsets — eliminates the
// returning-atomic reservation chain (R8 lesson: depth x ~184ns serial).
#define XB 6250            // N_NODES*FDIM/8/256 cast blocks
__global__ __launch_bounds__(256) void k_prep(
    const float* __restrict__ x, us16* __restrict__ xb, u8* __restrict__ xq,
    const float* __restrict__ Wrel1, const float* __restrict__ Wroot1,
    const float* __restrict__ Wrel2, const float* __restrict__ Wroot2,
    const float* __restrict__ Wrel3, const float* __restrict__ Wroot3,
    us16* __restrict__ Wp, float* __restrict__ pooled,
    const int* __restrict__ edst, int* __restrict__ bcnt,
    int* __restrict__ chist) {
  int bx = blockIdx.x, tid = threadIdx.x;
  if (bx < XB) {
    size_t i = ((size_t)bx * 256 + tid) * 8;    // 8 floats per thread
    float4 a = *(const float4*)(x + i);
    float4 b = *(const float4*)(x + i + 4);
    usx8 o;
    o[0]=f2bf(a.x); o[1]=f2bf(a.y); o[2]=f2bf(a.z); o[3]=f2bf(a.w);
    o[4]=f2bf(b.x); o[5]=f2bf(b.y); o[6]=f2bf(b.z); o[7]=f2bf(b.w);
    *(usx8*)(xb + i) = o;
    int lo = __builtin_amdgcn_cvt_pk_fp8_f32(a.x, a.y, 0, false);
    lo     = __builtin_amdgcn_cvt_pk_fp8_f32(a.z, a.w, lo, true);
    int hi = __builtin_amdgcn_cvt_pk_fp8_f32(b.x, b.y, 0, false);
    hi     = __builtin_amdgcn_cvt_pk_fp8_f32(b.z, b.w, hi, true);
    uint2 q; q.x = (unsigned)lo; q.y = (unsigned)hi;
    *(uint2*)(xq + i) = q;                       // 8 B contiguous per thread
  } else if (bx < XB + 384) {
    int wb = bx - XB;             // 0..383
    int l = wb >> 7;              // layer
    const float* Wrel  = (l == 0) ? Wrel1  : (l == 1) ? Wrel2  : Wrel3;
    const float* Wroot = (l == 0) ? Wroot1 : (l == 1) ? Wroot2 : Wroot3;
    int idx = (wb & 127) * 256 + tid;   // 0..32767
    int k = idx >> 7;       // 0..255
    int c = idx & 127;      // output col
    float v = (k < 128) ? Wrel[c * 128 + k] : Wroot[c * 128 + k - 128];
    Wp[(size_t)l * 32768 + (((k >> 3) * 128 + c) << 3) + (k & 7)] = f2bf(v);
  } else if (bx == XB + 384) {
    for (int i = tid; i < GDIM * FDIM; i += 256) pooled[i] = 0.f;
  } else {
    // bucket histogram over edge chunk; store per-chunk row + accumulate bcnt
    __shared__ int h[NB];
    int cb = bx - (XB + 385);
    for (int i = tid; i < NB; i += 256) h[i] = 0;
    __syncthreads();
    int s0 = cb * EPB;
    int e0 = s0 + EPB; if (e0 > N_EDGES) e0 = N_EDGES;
    for (int i = s0 + tid; i < e0; i += 256) atomicAdd(&h[edst[i] >> BSH], 1);
    __syncthreads();
    for (int i = tid; i < NB; i += 256) {
      chist[cb * NB + i] = h[i];               // coalesced, non-atomic
      if (h[i]) atomicAdd(&bcnt[i], h[i]);     // non-returning: pipelines OK
    }
  }
}

// In-block exclusive scan of bcnt[NB] -> boffL (LDS), wave-shuffle based.
__device__ __forceinline__ void scan_bcnt(const int* __restrict__ bcnt,
                                          int* wsum /*[>=4]*/,
                                          int* boffL /*[NB]*/, int tid) {
  int v = (tid < NB) ? bcnt[tid] : 0;
  int lane = tid & 63;
  int x = v;
#pragma unroll
  for (int d = 1; d < 64; d <<= 1) {
    int t = __shfl_up(x, d, 64);
    if (lane >= d) x += t;
  }
  if (tid < 256 && lane == 63) wsum[tid >> 6] = x;
  __syncthreads();
  if (tid == 0) {
    int r = 0;
#pragma unroll
    for (int i = 0; i < 4; ++i) { int t = wsum[i]; wsum[i] = r; r += t; }
  }
  __syncthreads();
  if (tid < NB) boffL[tid] = x - v + wsum[tid >> 6];   // exclusive
  __syncthreads();
}

// Column scan: block i computes coff[c][i] = boff[i] + sum_{c'<c} chist[c'][i].
// 196 blocks x 256 threads; thread c holds chist[c][i] (strided 4B load).
__global__ __launch_bounds__(256) void k_cscan(
    const int* __restrict__ bcnt, const int* __restrict__ chist,
    int* __restrict__ coff) {
  __shared__ int wsum[4];
  __shared__ int boffL[NB];
  __shared__ int wfix[4];
  int i = blockIdx.x, tid = threadIdx.x;
  scan_bcnt(bcnt, wsum, boffL, tid);
  int v = (tid < NCH) ? chist[tid * NB + i] : 0;
  int lane = tid & 63;
  int x = v;
#pragma unroll
  for (int d = 1; d < 64; d <<= 1) {
    int t = __shfl_up(x, d, 64);
    if (lane >= d) x += t;
  }
  if (lane == 63) wfix[tid >> 6] = x;
  __syncthreads();
  if (tid == 0) {
    int r = 0;
#pragma unroll
    for (int k = 0; k < 4; ++k) { int t = wfix[k]; wfix[k] = r; r += t; }
  }
  __syncthreads();
  if (tid < NCH)
    coff[tid * NB + i] = boffL[i] + (x - v + wfix[tid >> 6]);
}

// Pass C: counting-sort edges into bucket-contiguous runs, deterministic
// offsets (no histogram pass, no reservation atomics). 196 chunks align
// exactly with prep's hist chunks. Record packed (src << 9) | dst_local.
__global__ __launch_bounds__(1024) void k_bscatter(
    const int* __restrict__ src, const int* __restrict__ dst,
    const int* __restrict__ coff, int* __restrict__ ebuf) {
  __shared__ int base[NB];
  __shared__ int lc[NB];
  int tid = threadIdx.x, cb = blockIdx.x;
  for (int i = tid; i < NB; i += 1024) {
    base[i] = coff[cb * NB + i];
    lc[i] = 0;
  }
  __syncthreads();
  int s0 = cb * EPB;
  int e0 = s0 + EPB; if (e0 > N_EDGES) e0 = N_EDGES;
  for (int i = s0 + tid; i < e0; i += 1024) {
    int d = dst[i];
    int b = d >> BSH;
    int lp = atomicAdd(&lc[b], 1);
    ebuf[base[b] + lp] = (src[i] << BSH) | (d & (BSIZE - 1));
  }
}

// Pass D: per-bucket histogram -> row_ptr, LDS-cursor scatter (R7 unchanged).
__global__ __launch_bounds__(1024) void k_bucket_csr(
    const int* __restrict__ ebuf, const int* __restrict__ bcnt,
    int* __restrict__ row_ptr, int* __restrict__ csr_src) {
  __shared__ int wsum[8];
  __shared__ int boffL[NB];
  __shared__ int hist[BSIZE];
  __shared__ int cur[BSIZE];
  __shared__ int se[2];
  int b = blockIdx.x, tid = threadIdx.x;
  if (tid < BSIZE) hist[tid] = 0;
  scan_bcnt(bcnt, wsum, boffL, tid);
  if (tid == 0) {
    se[0] = boffL[b];
    se[1] = (b + 1 < NB) ? boffL[b + 1] : N_EDGES;
    if (b == 0) row_ptr[N_NODES] = N_EDGES;
  }
  __syncthreads();
  int eoff = se[0], ecnt = se[1] - se[0];
  int base = b * BSIZE;
  for (int i = tid; i < ecnt; i += 1024)
    atomicAdd(&hist[ebuf[eoff + i] & (BSIZE - 1)], 1);
  __syncthreads();
  int v = (tid < BSIZE) ? hist[tid] : 0;
  int lane = tid & 63;
  int x = v;
#pragma unroll
  for (int d = 1; d < 64; d <<= 1) {
    int t = __shfl_up(x, d, 64);
    if (lane >= d) x += t;
  }
  if (tid < BSIZE && lane == 63) wsum[tid >> 6] = x;
  __syncthreads();
  if (tid == 0) {
    int r = 0;
#pragma unroll
    for (int i = 0; i < 8; ++i) { int t = wsum[i]; wsum[i] = r; r += t; }
  }
  __syncthreads();
  if (tid < BSIZE) {
    int ex = x - v + wsum[tid >> 6];
    int node = base + tid;
    if (node < N_NODES) row_ptr[node] = eoff + ex;
    cur[tid] = ex;
  }
  __syncthreads();
  for (int i = tid; i < ecnt; i += 1024) {
    int e = ebuf[eoff + i];
    int lp = atomicAdd(&cur[e & (BSIZE - 1)], 1);
    csr_src[eoff + lp] = e >> BSH;
  }
}

// ---------------- fused layer: fp8 gather-aggregate -> MFMA dual GEMM ---------
// out = relu(agg(hq_in) @ Wrel^T + hin @ Wroot^T + b).  (R7 unchanged, 72us)
#define ASTR 136
#define LROWS 128
__global__ __launch_bounds__(512) void k_layer(
    const us16* __restrict__ hin, const u8* __restrict__ hq_in,
    const us16* __restrict__ Wp, const float* __restrict__ bias,
    const int* __restrict__ row_ptr, const int* __restrict__ csr_src,
    us16* __restrict__ out, u8* __restrict__ hq_out,
    const int* __restrict__ batch, float* __restrict__ pooled) {
  __shared__ us16 As[LROWS * ASTR];   // 34.8 KB
  int tid = threadIdx.x;
  int node0 = blockIdx.x * LROWS;
  int slot = tid >> 4;      // 0..31: node slot within round
  int lane16 = tid & 15;    // feature octet
  const u8* gbase = hq_in + lane16 * 8;   // 8 fp8 features per lane

  // ---- phase 1: aggregate 128 nodes (4 rounds x 32 concurrent), fp8 rows ----
#pragma unroll 1
  for (int rnd = 0; rnd < 4; ++rnd) {
    int node = node0 + rnd * 32 + slot;
    float a[8];
#pragma unroll
    for (int j = 0; j < 8; ++j) a[j] = 0.f;
    if (node < N_NODES) {
      int s = row_ptr[node], e = row_ptr[node + 1];
      int p = s;
      for (; p + 4 <= e; p += 4) {
        int j0 = csr_src[p], j1 = csr_src[p + 1];
        int j2 = csr_src[p + 2], j3 = csr_src[p + 3];
        uint2 v0 = *(const uint2*)(gbase + (size_t)j0 * FDIM);
        uint2 v1 = *(const uint2*)(gbase + (size_t)j1 * FDIM);
        uint2 v2 = *(const uint2*)(gbase + (size_t)j2 * FDIM);
        uint2 v3 = *(const uint2*)(gbase + (size_t)j3 * FDIM);
        acc_fp8x8(v0, a); acc_fp8x8(v1, a);
        acc_fp8x8(v2, a); acc_fp8x8(v3, a);
      }
      for (; p < e; ++p) {
        int j = csr_src[p];
        uint2 v = *(const uint2*)(gbase + (size_t)j * FDIM);
        acc_fp8x8(v, a);
      }
    }
    usx8 o;
#pragma unroll
    for (int j = 0; j < 8; ++j) o[j] = f2bf(a[j]);
    *(usx8*)&As[(rnd * 32 + slot) * ASTR + lane16 * 8] = o;
  }
  __syncthreads();

  // ---- phase 2: MFMA.  A agg-half from LDS, root-half from global (bf16),
  //      W b-frags straight from L1/L2.
  int wave = tid >> 6, lane = tid & 63;
  int m = lane & 15, quad = lane >> 4;
  size_t rowA = (size_t)(node0 + wave * 16 + m);
  const us16* baseH = hin + rowA * FDIM + quad * 8;
  const us16* aldsb = &As[(wave * 16 + m) * ASTR + quad * 8];
  f32x4 acc[8];
#pragma unroll
  for (int t = 0; t < 8; ++t) acc[t] = (f32x4){0.f, 0.f, 0.f, 0.f};

#pragma unroll 1
  for (int c = 0; c < 8; ++c) {
    bfrag a;
    if (c < 4) a = *(const bfrag*)(aldsb + c * 32);
    else       a = *(const bfrag*)(baseH + (c - 4) * 32);
    int kq = c * 4 + quad;
    const us16* wbase = Wp + (((size_t)kq * 128 + m) << 3);
#pragma unroll
    for (int t = 0; t < 8; ++t) {
      bfrag b = *(const bfrag*)(wbase + t * 128);   // 16 cols * 8 j
      acc[t] = __builtin_amdgcn_mfma_f32_16x16x32_bf16(a, b, acc[t], 0, 0, 0);
    }
  }
  // epilogue: D lane mapping col = lane&15 (within t-tile), row = quad*4 + i
  int w16 = node0 + wave * 16;
  int orow0 = w16 + quad * 4;
  if (pooled == nullptr) {
#pragma unroll
    for (int t = 0; t < 8; ++t) {
      int col = t * 16 + m;
      float bv = bias[col];
#pragma unroll
      for (int i = 0; i < 4; ++i) {
        int r = orow0 + i;
        if (r < N_NODES) {
          float val = fmaxf(acc[t][i] + bv, 0.f);
          out[(size_t)r * FDIM + col] = f2bf(val);
          // fp8 copy for next layer's gather; wave covers full 128B rows.
          hq_out[(size_t)r * FDIM + col] =
              (u8)(__builtin_amdgcn_cvt_pk_fp8_f32(val, val, 0, false) & 0xFF);
        }
      }
    }
  } else {
    // fused mean-pool (sum phase): no global store of h3
    int rlast = w16 + 15;
    int gfirst = batch[(w16 < N_NODES) ? w16 : (N_NODES - 1)];
    int glast  = batch[(rlast < N_NODES) ? rlast : (N_NODES - 1)];
    bool uniform = (gfirst == glast) && (rlast < N_NODES);
    if (uniform) {
#pragma unroll
      for (int t = 0; t < 8; ++t) {
        int col = t * 16 + m;
        float bv = bias[col];
        float v = fmaxf(acc[t][0] + bv, 0.f) + fmaxf(acc[t][1] + bv, 0.f) +
                  fmaxf(acc[t][2] + bv, 0.f) + fmaxf(acc[t][3] + bv, 0.f);
        v += __shfl_xor(v, 16);
        v += __shfl_xor(v, 32);
        if (quad == 0) atomicAdd(&pooled[gfirst * FDIM + col], v);
      }
    } else {
      int g[4];
#pragma unroll
      for (int i = 0; i < 4; ++i) {
        int r = orow0 + i;
        g[i] = batch[(r < N_NODES) ? r : (N_NODES - 1)];
      }
#pragma unroll
      for (int t = 0; t < 8; ++t) {
        int col = t * 16 + m;
        float bv = bias[col];
#pragma unroll
        for (int i = 0; i < 4; ++i) {
          int r = orow0 + i;
          if (r < N_NODES)
            atomicAdd(&pooled[g[i] * FDIM + col], fmaxf(acc[t][i] + bv, 0.f));
        }
      }
    }
  }
}

// ---------------- MLP head + log_softmax (divides pooled sums by counts) ------
__global__ __launch_bounds__(128) void k_head(
    const float* __restrict__ pooled, const int* __restrict__ batch,
    const float* __restrict__ Wl1, const float* __restrict__ bl1,
    const float* __restrict__ Wl2, const float* __restrict__ bl2,
    float* __restrict__ out) {
  int g = blockIdx.x;
  __shared__ int sb[2];
  __shared__ float p[128];
  __shared__ float h1[64];
  __shared__ float logit[CDIM];
  if (threadIdx.x < 2) {
    int key = g + (int)threadIdx.x;
    int lo = 0, hi = N_NODES;
    while (lo < hi) {
      int mid = (lo + hi) >> 1;
      if (batch[mid] < key) lo = mid + 1; else hi = mid;
    }
    sb[threadIdx.x] = lo;
  }
  __syncthreads();
  float cnt = (float)(sb[1] - sb[0]);
  p[threadIdx.x] = pooled[g * FDIM + threadIdx.x] / fmaxf(cnt, 1.f);
  __syncthreads();
  if (threadIdx.x < 64) {
    float acc = bl1[threadIdx.x];
    for (int k = 0; k < 128; ++k) acc += p[k] * Wl1[threadIdx.x * 128 + k];
    h1[threadIdx.x] = fmaxf(acc, 0.f);
  }
  __syncthreads();
  if (threadIdx.x < CDIM) {
    float acc = bl2[threadIdx.x];
    for (int k = 0; k < 64; ++k) acc += h1[k] * Wl2[threadIdx.x * 64 + k];
    logit[threadIdx.x] = acc;
  }
  __syncthreads();
  if (threadIdx.x == 0) {
    float m = -1e30f;
    for (int c = 0; c < CDIM; ++c) m = fmaxf(m, logit[c]);
    float s = 0.f;
    for (int c = 0; c < CDIM; ++c) s += expf(logit[c] - m);
    float ls = logf(s);
    for (int c = 0; c < CDIM; ++c) out[g * CDIM + c] = logit[c] - m - ls;
  }
}

extern "C" void kernel_launch(void* const* d_in, const int* in_sizes, int n_in,
                              void* d_out, int out_size, void* d_ws, size_t ws_size,
                              hipStream_t stream) {
  const float* x      = (const float*)d_in[0];
  const int* edge_idx = (const int*)d_in[1];
  const int* batch    = (const int*)d_in[2];
  const float* W1_rel  = (const float*)d_in[4];
  const float* b1_rel  = (const float*)d_in[5];
  const float* W1_root = (const float*)d_in[6];
  const float* W2_rel  = (const float*)d_in[7];
  const float* b2_rel  = (const float*)d_in[8];
  const float* W2_root = (const float*)d_in[9];
  const float* W3_rel  = (const float*)d_in[10];
  const float* b3_rel  = (const float*)d_in[11];
  const float* W3_root = (const float*)d_in[12];
  const float* Wl1     = (const float*)d_in[13];
  const float* bl1     = (const float*)d_in[14];
  const float* Wl2     = (const float*)d_in[15];
  const float* bl2     = (const float*)d_in[16];
  const int* esrc = edge_idx;
  const int* edst = edge_idx + N_EDGES;

  char* ws = (char*)d_ws;
  size_t off = 0;
  auto alloc = [&](size_t bytes) {
    void* p = ws + off;
    off += (bytes + 255) & ~(size_t)255;
    return p;
  };
  int* row_ptr  = (int*)alloc((N_NODES + 1) * sizeof(int));
  int* bcnt     = (int*)alloc(NB * sizeof(int));
  int* chist    = (int*)alloc((size_t)NCH * NB * sizeof(int));   // 154 KB
  int* coff     = (int*)alloc((size_t)NCH * NB * sizeof(int));   // 154 KB
  int* csr_src  = (int*)alloc(N_EDGES * sizeof(int));
  us16* xb      = (us16*)alloc((size_t)NPAD * FDIM * sizeof(us16)); // h0, then h2
  us16* hA      = (us16*)alloc((size_t)NPAD * FDIM * sizeof(us16)); // h1
  u8*   xq      = (u8*)alloc((size_t)NPAD * FDIM);                  // q0, then q2
  u8*   hqA     = (u8*)alloc((size_t)NPAD * FDIM);                  // q1
  us16* Wp      = (us16*)alloc(3 * 32768 * sizeof(us16));
  float* pooled = (float*)alloc(GDIM * FDIM * sizeof(float));
  // ebuf (6.4 MB, packed) aliases hA (25.6 MB): dead before layer-1 writes hA
  int* ebuf     = (int*)hA;

  hipMemsetAsync(bcnt, 0, NB * sizeof(int), stream);

  // prep: cast x (bf16+fp8), pack W, zero pooled, per-chunk histograms
  k_prep<<<XB + 385 + NCH, 256, 0, stream>>>(
      x, xb, xq, W1_rel, W1_root, W2_rel, W2_root, W3_rel, W3_root, Wp, pooled,
      edst, bcnt, chist);

  // deterministic offsets: column scan of per-chunk hist
  k_cscan<<<NB, 256, 0, stream>>>(bcnt, chist, coff);
  // scatter with precomputed bases (no histogram pass, no reservation chain)
  k_bscatter<<<NCH, 1024, 0, stream>>>(esrc, edst, coff, ebuf);
  k_bucket_csr<<<NB, 1024, 0, stream>>>(ebuf, bcnt, row_ptr, csr_src);

  int lgrid = NPAD / LROWS;                // 782
  // layer 1: gather q0, root xb -> h1 (hA bf16 + hqA fp8)
  k_layer<<<lgrid, 512, 0, stream>>>(xb, xq, Wp, b1_rel, row_ptr, csr_src,
                                     hA, hqA, batch, nullptr);
  // layer 2: gather q1, root hA -> h2 (xb bf16 + xq fp8; dead inputs reused)
  k_layer<<<lgrid, 512, 0, stream>>>(hA, hqA, Wp + 32768, b2_rel, row_ptr,
                                     csr_src, xb, xq, batch, nullptr);
  // layer 3: gather q2, root xb -> pooled sums (no h3 store)
  k_layer<<<lgrid, 512, 0, stream>>>(xb, xq, Wp + 65536, b3_rel, row_ptr,
                                     csr_src, hA, nullptr, batch, pooled);

  k_head<<<GDIM, 128, 0, stream>>>(pooled, batch, Wl1, bl1, Wl2, bl2, (float*)d_out);
}

// Round 10
// 370.061 us; speedup vs baseline: 1.9564x; 1.0220x over previous
//
#include <hip/hip_runtime.h>

#define N_NODES 100000
#define NPAD    100096      // multiple of 128 so layer blocks need no row clamp
#define N_EDGES 1600000
#define FDIM 128
#define GDIM 64
#define CDIM 10

#define BSH   9
#define BSIZE 512           // nodes per bucket
#define NB    196           // ceil(N_NODES / BSIZE)
#define EPB   8192          // edges per chunk (prep hist AND bscatter) -> 196 chunks
#define NCH   196           // ceil(N_EDGES / EPB)

typedef unsigned short us16;
typedef unsigned char u8;
typedef us16 usx8 __attribute__((ext_vector_type(8)));
typedef short bfrag __attribute__((ext_vector_type(8)));   // 8 bf16 = 4 VGPRs
typedef float f32x4 __attribute__((ext_vector_type(4)));
typedef float f32x2 __attribute__((ext_vector_type(2)));

__device__ __forceinline__ float bf2f(us16 u) {
  return __uint_as_float(((unsigned)u) << 16);
}
__device__ __forceinline__ us16 f2bf(float f) {
  unsigned u = __float_as_uint(f);
  u += 0x7FFFu + ((u >> 16) & 1u);   // RNE
  return (us16)(u >> 16);
}

// accumulate 8 fp8 (e4m3, one uint2) into a[0..8)
__device__ __forceinline__ void acc_fp8x8(uint2 v, float* a) {
  f32x2 p0 = __builtin_amdgcn_cvt_pk_f32_fp8(v.x, false);
  f32x2 p1 = __builtin_amdgcn_cvt_pk_f32_fp8(v.x, true);
  f32x2 p2 = __builtin_amdgcn_cvt_pk_f32_fp8(v.y, false);
  f32x2 p3 = __builtin_amdgcn_cvt_pk_f32_fp8(v.y, true);
  a[0] += p0[0]; a[1] += p0[1]; a[2] += p1[0]; a[3] += p1[1];
  a[4] += p2[0]; a[5] += p2[1]; a[6] += p3[0]; a[7] += p3[1];
}

// ---------------- prep: cast x (bf16 + fp8), pack W, zero pooled, histogram ---
// bcnt zeroed by memsetAsync BEFORE this kernel.
#define XB 6250            // N_NODES*FDIM/8/256 cast blocks
__global__ __launch_bounds__(256) void k_prep(
    const float* __restrict__ x, us16* __restrict__ xb, u8* __restrict__ xq,
    const float* __restrict__ Wrel1, const float* __restrict__ Wroot1,
    const float* __restrict__ Wrel2, const float* __restrict__ Wroot2,
    const float* __restrict__ Wrel3, const float* __restrict__ Wroot3,
    us16* __restrict__ Wp, float* __restrict__ pooled,
    const int* __restrict__ edst, int* __restrict__ bcnt,
    int* __restrict__ chist) {
  int bx = blockIdx.x, tid = threadIdx.x;
  if (bx < XB) {
    size_t i = ((size_t)bx * 256 + tid) * 8;    // 8 floats per thread
    float4 a = *(const float4*)(x + i);
    float4 b = *(const float4*)(x + i + 4);
    usx8 o;
    o[0]=f2bf(a.x); o[1]=f2bf(a.y); o[2]=f2bf(a.z); o[3]=f2bf(a.w);
    o[4]=f2bf(b.x); o[5]=f2bf(b.y); o[6]=f2bf(b.z); o[7]=f2bf(b.w);
    *(usx8*)(xb + i) = o;
    int lo = __builtin_amdgcn_cvt_pk_fp8_f32(a.x, a.y, 0, false);
    lo     = __builtin_amdgcn_cvt_pk_fp8_f32(a.z, a.w, lo, true);
    int hi = __builtin_amdgcn_cvt_pk_fp8_f32(b.x, b.y, 0, false);
    hi     = __builtin_amdgcn_cvt_pk_fp8_f32(b.z, b.w, hi, true);
    uint2 q; q.x = (unsigned)lo; q.y = (unsigned)hi;
    *(uint2*)(xq + i) = q;                       // 8 B contiguous per thread
  } else if (bx < XB + 384) {
    int wb = bx - XB;             // 0..383
    int l = wb >> 7;              // layer
    const float* Wrel  = (l == 0) ? Wrel1  : (l == 1) ? Wrel2  : Wrel3;
    const float* Wroot = (l == 0) ? Wroot1 : (l == 1) ? Wroot2 : Wroot3;
    int idx = (wb & 127) * 256 + tid;   // 0..32767
    int k = idx >> 7;       // 0..255
    int c = idx & 127;      // output col
    float v = (k < 128) ? Wrel[c * 128 + k] : Wroot[c * 128 + k - 128];
    Wp[(size_t)l * 32768 + (((k >> 3) * 128 + c) << 3) + (k & 7)] = f2bf(v);
  } else if (bx == XB + 384) {
    for (int i = tid; i < GDIM * FDIM; i += 256) pooled[i] = 0.f;
  } else {
    // bucket histogram over edge chunk; store per-chunk row + accumulate bcnt
    __shared__ int h[NB];
    int cb = bx - (XB + 385);
    for (int i = tid; i < NB; i += 256) h[i] = 0;
    __syncthreads();
    int s0 = cb * EPB;
    int e0 = s0 + EPB; if (e0 > N_EDGES) e0 = N_EDGES;
    for (int i = s0 + tid; i < e0; i += 256) atomicAdd(&h[edst[i] >> BSH], 1);
    __syncthreads();
    for (int i = tid; i < NB; i += 256) {
      chist[cb * NB + i] = h[i];               // coalesced, non-atomic
      if (h[i]) atomicAdd(&bcnt[i], h[i]);     // non-returning: pipelines OK
    }
  }
}

// In-block exclusive scan of bcnt[NB] -> boffL (LDS), wave-shuffle based.
__device__ __forceinline__ void scan_bcnt(const int* __restrict__ bcnt,
                                          int* wsum /*[>=4]*/,
                                          int* boffL /*[NB]*/, int tid) {
  int v = (tid < NB) ? bcnt[tid] : 0;
  int lane = tid & 63;
  int x = v;
#pragma unroll
  for (int d = 1; d < 64; d <<= 1) {
    int t = __shfl_up(x, d, 64);
    if (lane >= d) x += t;
  }
  if (tid < 256 && lane == 63) wsum[tid >> 6] = x;
  __syncthreads();
  if (tid == 0) {
    int r = 0;
#pragma unroll
    for (int i = 0; i < 4; ++i) { int t = wsum[i]; wsum[i] = r; r += t; }
  }
  __syncthreads();
  if (tid < NB) boffL[tid] = x - v + wsum[tid >> 6];   // exclusive
  __syncthreads();
}

// Column scan: block i computes coff[c][i] = boff[i] + sum_{c'<c} chist[c'][i].
__global__ __launch_bounds__(256) void k_cscan(
    const int* __restrict__ bcnt, const int* __restrict__ chist,
    int* __restrict__ coff) {
  __shared__ int wsum[4];
  __shared__ int boffL[NB];
  __shared__ int wfix[4];
  int i = blockIdx.x, tid = threadIdx.x;
  scan_bcnt(bcnt, wsum, boffL, tid);
  int v = (tid < NCH) ? chist[tid * NB + i] : 0;
  int lane = tid & 63;
  int x = v;
#pragma unroll
  for (int d = 1; d < 64; d <<= 1) {
    int t = __shfl_up(x, d, 64);
    if (lane >= d) x += t;
  }
  if (lane == 63) wfix[tid >> 6] = x;
  __syncthreads();
  if (tid == 0) {
    int r = 0;
#pragma unroll
    for (int k = 0; k < 4; ++k) { int t = wfix[k]; wfix[k] = r; r += t; }
  }
  __syncthreads();
  if (tid < NCH)
    coff[tid * NB + i] = boffL[i] + (x - v + wfix[tid >> 6]);
}

// Pass C: counting-sort edges into bucket-contiguous runs, deterministic
// offsets (no histogram pass, no reservation atomics).
__global__ __launch_bounds__(1024) void k_bscatter(
    const int* __restrict__ src, const int* __restrict__ dst,
    const int* __restrict__ coff, int* __restrict__ ebuf) {
  __shared__ int base[NB];
  __shared__ int lc[NB];
  int tid = threadIdx.x, cb = blockIdx.x;
  for (int i = tid; i < NB; i += 1024) {
    base[i] = coff[cb * NB + i];
    lc[i] = 0;
  }
  __syncthreads();
  int s0 = cb * EPB;
  int e0 = s0 + EPB; if (e0 > N_EDGES) e0 = N_EDGES;
  for (int i = s0 + tid; i < e0; i += 1024) {
    int d = dst[i];
    int b = d >> BSH;
    int lp = atomicAdd(&lc[b], 1);
    ebuf[base[b] + lp] = (src[i] << BSH) | (d & (BSIZE - 1));
  }
}

// Pass D: per-bucket histogram -> row_ptr, LDS-cursor scatter.
__global__ __launch_bounds__(1024) void k_bucket_csr(
    const int* __restrict__ ebuf, const int* __restrict__ bcnt,
    int* __restrict__ row_ptr, int* __restrict__ csr_src) {
  __shared__ int wsum[8];
  __shared__ int boffL[NB];
  __shared__ int hist[BSIZE];
  __shared__ int cur[BSIZE];
  __shared__ int se[2];
  int b = blockIdx.x, tid = threadIdx.x;
  if (tid < BSIZE) hist[tid] = 0;
  scan_bcnt(bcnt, wsum, boffL, tid);
  if (tid == 0) {
    se[0] = boffL[b];
    se[1] = (b + 1 < NB) ? boffL[b + 1] : N_EDGES;
    if (b == 0) row_ptr[N_NODES] = N_EDGES;
  }
  __syncthreads();
  int eoff = se[0], ecnt = se[1] - se[0];
  int base = b * BSIZE;
  for (int i = tid; i < ecnt; i += 1024)
    atomicAdd(&hist[ebuf[eoff + i] & (BSIZE - 1)], 1);
  __syncthreads();
  int v = (tid < BSIZE) ? hist[tid] : 0;
  int lane = tid & 63;
  int x = v;
#pragma unroll
  for (int d = 1; d < 64; d <<= 1) {
    int t = __shfl_up(x, d, 64);
    if (lane >= d) x += t;
  }
  if (tid < BSIZE && lane == 63) wsum[tid >> 6] = x;
  __syncthreads();
  if (tid == 0) {
    int r = 0;
#pragma unroll
    for (int i = 0; i < 8; ++i) { int t = wsum[i]; wsum[i] = r; r += t; }
  }
  __syncthreads();
  if (tid < BSIZE) {
    int ex = x - v + wsum[tid >> 6];
    int node = base + tid;
    if (node < N_NODES) row_ptr[node] = eoff + ex;
    cur[tid] = ex;
  }
  __syncthreads();
  for (int i = tid; i < ecnt; i += 1024) {
    int e = ebuf[eoff + i];
    int lp = atomicAdd(&cur[e & (BSIZE - 1)], 1);
    csr_src[eoff + lp] = e >> BSH;
  }
}

// ---------------- fused layer: fp8 gather-aggregate -> MFMA dual GEMM ---------
// out = relu(agg(hq_in) @ Wrel^T + hin @ Wroot^T + b).
// R10: phase-1 main loop deepened 4 -> 8 edges in flight. Little's-law fit of
// R7/R9 (0.47 loads/cyc/CU = 16 waves x 16 in-flight / ~600cy) showed the
// gather is concurrency-limited by unroll depth, not traffic (1.35 < 2.2 TB/s
// random tier) and not round structure (no barriers between rounds).
#define ASTR 136
#define LROWS 128
__global__ __launch_bounds__(512) void k_layer(
    const us16* __restrict__ hin, const u8* __restrict__ hq_in,
    const us16* __restrict__ Wp, const float* __restrict__ bias,
    const int* __restrict__ row_ptr, const int* __restrict__ csr_src,
    us16* __restrict__ out, u8* __restrict__ hq_out,
    const int* __restrict__ batch, float* __restrict__ pooled) {
  __shared__ us16 As[LROWS * ASTR];   // 34.8 KB
  int tid = threadIdx.x;
  int node0 = blockIdx.x * LROWS;
  int slot = tid >> 4;      // 0..31: node slot within round
  int lane16 = tid & 15;    // feature octet
  const u8* gbase = hq_in + lane16 * 8;   // 8 fp8 features per lane

  // ---- phase 1: aggregate 128 nodes (4 rounds x 32 concurrent), fp8 rows ----
#pragma unroll 1
  for (int rnd = 0; rnd < 4; ++rnd) {
    int node = node0 + rnd * 32 + slot;
    float a[8];
#pragma unroll
    for (int j = 0; j < 8; ++j) a[j] = 0.f;
    if (node < N_NODES) {
      int s = row_ptr[node], e = row_ptr[node + 1];
      int p = s;
      // 8-deep: 8 index loads + 8 gathers issued before any consumption
      for (; p + 8 <= e; p += 8) {
        int j0 = csr_src[p],     j1 = csr_src[p + 1];
        int j2 = csr_src[p + 2], j3 = csr_src[p + 3];
        int j4 = csr_src[p + 4], j5 = csr_src[p + 5];
        int j6 = csr_src[p + 6], j7 = csr_src[p + 7];
        uint2 v0 = *(const uint2*)(gbase + (size_t)j0 * FDIM);
        uint2 v1 = *(const uint2*)(gbase + (size_t)j1 * FDIM);
        uint2 v2 = *(const uint2*)(gbase + (size_t)j2 * FDIM);
        uint2 v3 = *(const uint2*)(gbase + (size_t)j3 * FDIM);
        uint2 v4 = *(const uint2*)(gbase + (size_t)j4 * FDIM);
        uint2 v5 = *(const uint2*)(gbase + (size_t)j5 * FDIM);
        uint2 v6 = *(const uint2*)(gbase + (size_t)j6 * FDIM);
        uint2 v7 = *(const uint2*)(gbase + (size_t)j7 * FDIM);
        acc_fp8x8(v0, a); acc_fp8x8(v1, a);
        acc_fp8x8(v2, a); acc_fp8x8(v3, a);
        acc_fp8x8(v4, a); acc_fp8x8(v5, a);
        acc_fp8x8(v6, a); acc_fp8x8(v7, a);
      }
      for (; p + 4 <= e; p += 4) {
        int j0 = csr_src[p], j1 = csr_src[p + 1];
        int j2 = csr_src[p + 2], j3 = csr_src[p + 3];
        uint2 v0 = *(const uint2*)(gbase + (size_t)j0 * FDIM);
        uint2 v1 = *(const uint2*)(gbase + (size_t)j1 * FDIM);
        uint2 v2 = *(const uint2*)(gbase + (size_t)j2 * FDIM);
        uint2 v3 = *(const uint2*)(gbase + (size_t)j3 * FDIM);
        acc_fp8x8(v0, a); acc_fp8x8(v1, a);
        acc_fp8x8(v2, a); acc_fp8x8(v3, a);
      }
      for (; p < e; ++p) {
        int j = csr_src[p];
        uint2 v = *(const uint2*)(gbase + (size_t)j * FDIM);
        acc_fp8x8(v, a);
      }
    }
    usx8 o;
#pragma unroll
    for (int j = 0; j < 8; ++j) o[j] = f2bf(a[j]);
    *(usx8*)&As[(rnd * 32 + slot) * ASTR + lane16 * 8] = o;
  }
  __syncthreads();

  // ---- phase 2: MFMA.  A agg-half from LDS, root-half from global (bf16),
  //      W b-frags straight from L1/L2.
  int wave = tid >> 6, lane = tid & 63;
  int m = lane & 15, quad = lane >> 4;
  size_t rowA = (size_t)(node0 + wave * 16 + m);
  const us16* baseH = hin + rowA * FDIM + quad * 8;
  const us16* aldsb = &As[(wave * 16 + m) * ASTR + quad * 8];
  f32x4 acc[8];
#pragma unroll
  for (int t = 0; t < 8; ++t) acc[t] = (f32x4){0.f, 0.f, 0.f, 0.f};

#pragma unroll 1
  for (int c = 0; c < 8; ++c) {
    bfrag a;
    if (c < 4) a = *(const bfrag*)(aldsb + c * 32);
    else       a = *(const bfrag*)(baseH + (c - 4) * 32);
    int kq = c * 4 + quad;
    const us16* wbase = Wp + (((size_t)kq * 128 + m) << 3);
#pragma unroll
    for (int t = 0; t < 8; ++t) {
      bfrag b = *(const bfrag*)(wbase + t * 128);   // 16 cols * 8 j
      acc[t] = __builtin_amdgcn_mfma_f32_16x16x32_bf16(a, b, acc[t], 0, 0, 0);
    }
  }
  // epilogue: D lane mapping col = lane&15 (within t-tile), row = quad*4 + i
  int w16 = node0 + wave * 16;
  int orow0 = w16 + quad * 4;
  if (pooled == nullptr) {
#pragma unroll
    for (int t = 0; t < 8; ++t) {
      int col = t * 16 + m;
      float bv = bias[col];
#pragma unroll
      for (int i = 0; i < 4; ++i) {
        int r = orow0 + i;
        if (r < N_NODES) {
          float val = fmaxf(acc[t][i] + bv, 0.f);
          out[(size_t)r * FDIM + col] = f2bf(val);
          // fp8 copy for next layer's gather; wave covers full 128B rows.
          hq_out[(size_t)r * FDIM + col] =
              (u8)(__builtin_amdgcn_cvt_pk_fp8_f32(val, val, 0, false) & 0xFF);
        }
      }
    }
  } else {
    // fused mean-pool (sum phase): no global store of h3
    int rlast = w16 + 15;
    int gfirst = batch[(w16 < N_NODES) ? w16 : (N_NODES - 1)];
    int glast  = batch[(rlast < N_NODES) ? rlast : (N_NODES - 1)];
    bool uniform = (gfirst == glast) && (rlast < N_NODES);
    if (uniform) {
#pragma unroll
      for (int t = 0; t < 8; ++t) {
        int col = t * 16 + m;
        float bv = bias[col];
        float v = fmaxf(acc[t][0] + bv, 0.f) + fmaxf(acc[t][1] + bv, 0.f) +
                  fmaxf(acc[t][2] + bv, 0.f) + fmaxf(acc[t][3] + bv, 0.f);
        v += __shfl_xor(v, 16);
        v += __shfl_xor(v, 32);
        if (quad == 0) atomicAdd(&pooled[gfirst * FDIM + col], v);
      }
    } else {
      int g[4];
#pragma unroll
      for (int i = 0; i < 4; ++i) {
        int r = orow0 + i;
        g[i] = batch[(r < N_NODES) ? r : (N_NODES - 1)];
      }
#pragma unroll
      for (int t = 0; t < 8; ++t) {
        int col = t * 16 + m;
        float bv = bias[col];
#pragma unroll
        for (int i = 0; i < 4; ++i) {
          int r = orow0 + i;
          if (r < N_NODES)
            atomicAdd(&pooled[g[i] * FDIM + col], fmaxf(acc[t][i] + bv, 0.f));
        }
      }
    }
  }
}

// ---------------- MLP head + log_softmax (divides pooled sums by counts) ------
__global__ __launch_bounds__(128) void k_head(
    const float* __restrict__ pooled, const int* __restrict__ batch,
    const float* __restrict__ Wl1, const float* __restrict__ bl1,
    const float* __restrict__ Wl2, const float* __restrict__ bl2,
    float* __restrict__ out) {
  int g = blockIdx.x;
  __shared__ int sb[2];
  __shared__ float p[128];
  __shared__ float h1[64];
  __shared__ float logit[CDIM];
  if (threadIdx.x < 2) {
    int key = g + (int)threadIdx.x;
    int lo = 0, hi = N_NODES;
    while (lo < hi) {
      int mid = (lo + hi) >> 1;
      if (batch[mid] < key) lo = mid + 1; else hi = mid;
    }
    sb[threadIdx.x] = lo;
  }
  __syncthreads();
  float cnt = (float)(sb[1] - sb[0]);
  p[threadIdx.x] = pooled[g * FDIM + threadIdx.x] / fmaxf(cnt, 1.f);
  __syncthreads();
  if (threadIdx.x < 64) {
    float acc = bl1[threadIdx.x];
    for (int k = 0; k < 128; ++k) acc += p[k] * Wl1[threadIdx.x * 128 + k];
    h1[threadIdx.x] = fmaxf(acc, 0.f);
  }
  __syncthreads();
  if (threadIdx.x < CDIM) {
    float acc = bl2[threadIdx.x];
    for (int k = 0; k < 64; ++k) acc += h1[k] * Wl2[threadIdx.x * 64 + k];
    logit[threadIdx.x] = acc;
  }
  __syncthreads();
  if (threadIdx.x == 0) {
    float m = -1e30f;
    for (int c = 0; c < CDIM; ++c) m = fmaxf(m, logit[c]);
    float s = 0.f;
    for (int c = 0; c < CDIM; ++c) s += expf(logit[c] - m);
    float ls = logf(s);
    for (int c = 0; c < CDIM; ++c) out[g * CDIM + c] = logit[c] - m - ls;
  }
}

extern "C" void kernel_launch(void* const* d_in, const int* in_sizes, int n_in,
                              void* d_out, int out_size, void* d_ws, size_t ws_size,
                              hipStream_t stream) {
  const float* x      = (const float*)d_in[0];
  const int* edge_idx = (const int*)d_in[1];
  const int* batch    = (const int*)d_in[2];
  const float* W1_rel  = (const float*)d_in[4];
  const float* b1_rel  = (const float*)d_in[5];
  const float* W1_root = (const float*)d_in[6];
  const float* W2_rel  = (const float*)d_in[7];
  const float* b2_rel  = (const float*)d_in[8];
  const float* W2_root = (const float*)d_in[9];
  const float* W3_rel  = (const float*)d_in[10];
  const float* b3_rel  = (const float*)d_in[11];
  const float* W3_root = (const float*)d_in[12];
  const float* Wl1     = (const float*)d_in[13];
  const float* bl1     = (const float*)d_in[14];
  const float* Wl2     = (const float*)d_in[15];
  const float* bl2     = (const float*)d_in[16];
  const int* esrc = edge_idx;
  const int* edst = edge_idx + N_EDGES;

  char* ws = (char*)d_ws;
  size_t off = 0;
  auto alloc = [&](size_t bytes) {
    void* p = ws + off;
    off += (bytes + 255) & ~(size_t)255;
    return p;
  };
  int* row_ptr  = (int*)alloc((N_NODES + 1) * sizeof(int));
  int* bcnt     = (int*)alloc(NB * sizeof(int));
  int* chist    = (int*)alloc((size_t)NCH * NB * sizeof(int));   // 154 KB
  int* coff     = (int*)alloc((size_t)NCH * NB * sizeof(int));   // 154 KB
  int* csr_src  = (int*)alloc(N_EDGES * sizeof(int));
  us16* xb      = (us16*)alloc((size_t)NPAD * FDIM * sizeof(us16)); // h0, then h2
  us16* hA      = (us16*)alloc((size_t)NPAD * FDIM * sizeof(us16)); // h1
  u8*   xq      = (u8*)alloc((size_t)NPAD * FDIM);                  // q0, then q2
  u8*   hqA     = (u8*)alloc((size_t)NPAD * FDIM);                  // q1
  us16* Wp      = (us16*)alloc(3 * 32768 * sizeof(us16));
  float* pooled = (float*)alloc(GDIM * FDIM * sizeof(float));
  // ebuf (6.4 MB, packed) aliases hA (25.6 MB): dead before layer-1 writes hA
  int* ebuf     = (int*)hA;

  hipMemsetAsync(bcnt, 0, NB * sizeof(int), stream);

  // prep: cast x (bf16+fp8), pack W, zero pooled, per-chunk histograms
  k_prep<<<XB + 385 + NCH, 256, 0, stream>>>(
      x, xb, xq, W1_rel, W1_root, W2_rel, W2_root, W3_rel, W3_root, Wp, pooled,
      edst, bcnt, chist);

  // deterministic offsets: column scan of per-chunk hist
  k_cscan<<<NB, 256, 0, stream>>>(bcnt, chist, coff);
  // scatter with precomputed bases (no histogram pass, no reservation chain)
  k_bscatter<<<NCH, 1024, 0, stream>>>(esrc, edst, coff, ebuf);
  k_bucket_csr<<<NB, 1024, 0, stream>>>(ebuf, bcnt, row_ptr, csr_src);

  int lgrid = NPAD / LROWS;                // 782
  // layer 1: gather q0, root xb -> h1 (hA bf16 + hqA fp8)
  k_layer<<<lgrid, 512, 0, stream>>>(xb, xq, Wp, b1_rel, row_ptr, csr_src,
                                     hA, hqA, batch, nullptr);
  // layer 2: gather q1, root hA -> h2 (xb bf16 + xq fp8; dead inputs reused)
  k_layer<<<lgrid, 512, 0, stream>>>(hA, hqA, Wp + 32768, b2_rel, row_ptr,
                                     csr_src, xb, xq, batch, nullptr);
  // layer 3: gather q2, root xb -> pooled sums (no h3 store)
  k_layer<<<lgrid, 512, 0, stream>>>(xb, xq, Wp + 65536, b3_rel, row_ptr,
                                     csr_src, hA, nullptr, batch, pooled);

  k_head<<<GDIM, 128, 0, stream>>>(pooled, batch, Wl1, bl1, Wl2, bl2, (float*)d_out);
}